// Round 5
// baseline (729.520 us; speedup 1.0000x reference)
//
#include <hip/hip_runtime.h>
#include <stdint.h>

// Keep every f32 op un-fused: the reference (numpy/jax f32) computes
// inter = ih*iw; union = a_i + a_j - inter as separate rounded ops. With
// HIP's default -ffp-contract=fast the subtract would fuse into an FMA and
// could flip borderline iou > 0.5 decisions -> wrong box selected.
#pragma clang fp contract(off)

namespace {
constexpr int kN = 21824;      // 128^2 + 64^2 + 32^2 + 16^2 + 8^2
constexpr int kB = 16;
constexpr int kC = 80;
constexpr int kK = 256;        // K_CAND
constexpr int kMaxPC = 100;
constexpr int kMaxDet = 100;
constexpr int kBins1 = 2048;   // fallback histogram bins (top 11 score bits)
constexpr int kCap = 1536;     // per-row candidate capacity (u64 keys)
constexpr int kRows = kB * kC; // 1280
// Prune floor for the fast path. For this benchmark's product-of-uniforms
// scores, #(s > 0.72) per row ~ Binomial(21824, 0.0435): mean ~950, sd ~30 —
// inside [kK, kCap] with ~10-sigma margin. ANY input where the count lands
// outside falls back to the exact column re-scan, so this is a speed
// heuristic only, never a correctness assumption.
constexpr float kThr = 0.72f;
// Exact iou>0.5 without division: RN(inter/unc) > 0.5  <=>  inter > (0.5+2^-25)*unc.
// (0.5+2^-25)*unc is exact in double (25b x 24b mantissa <= 49b); the tie at
// q = 0.5+2^-25 rounds-to-even down to 0.5, so the strict > matches exactly.
constexpr double kIouC = 0x1.000001p-1;   // 0.5 + 2^-25
}

// ---- 48-bit sort key: score bits (high 32) | (0xFFFF - index) (low 16) ----
// scores are >= 0 so the raw f32 bit pattern is order-monotone; the index
// complement reproduces jax top_k's stable tie-break (lower index wins).
__device__ __forceinline__ uint64_t make_key(float s, int n) {
  return ((uint64_t)__float_as_uint(s) << 16) | (uint32_t)(0xFFFF - n);
}

// Block-wide (256 threads) inclusive prefix scan.
__device__ uint32_t block_scan_incl(uint32_t val) {
  __shared__ uint32_t wsum[4];
  int lane = threadIdx.x & 63;
  int wave = threadIdx.x >> 6;
  for (int d = 1; d < 64; d <<= 1) {
    uint32_t t = __shfl_up(val, (unsigned)d, 64);
    if (lane >= d) val += t;
  }
  if (lane == 63) wsum[wave] = val;
  __syncthreads();
  uint32_t off = 0;
  for (int w = 0; w < wave; ++w) off += wsum[w];
  __syncthreads();
  return val + off;
}

// ---- exact fallback: gather a <=kCap superset of the top-256 keys of one
// class column directly from clfs/ctrs (strided reads; slow but bit-exact).
__device__ int fallback_gather(const float* __restrict__ clfs,
                               const float* __restrict__ ctrs, int b, int c,
                               uint32_t* hist, uint64_t* keybuf) {
  __shared__ int fsel_bin;
  __shared__ uint32_t fsel_hd, fsel_above, fcnt;
  int tid = threadIdx.x;
  const float* cl = clfs + (size_t)b * kN * kC + c;
  const float* ct = ctrs + (size_t)b * kN;

  // pass 1: 2048-bin histogram over score bits >> 21 (= key bits [37..48))
  for (int i = tid; i < kBins1; i += 256) hist[i] = 0;
  __syncthreads();
  for (int n = tid; n < kN; n += 256) {
    float s = cl[(size_t)n * kC] * ct[n];
    atomicAdd(&hist[__float_as_uint(s) >> 21], 1u);
  }
  __syncthreads();
  uint32_t krem = kK;
  {
    uint32_t bl[8], v = 0;
    int base = kBins1 - 1 - 8 * tid;
    for (int j = 0; j < 8; ++j) { bl[j] = hist[base - j]; v += bl[j]; }
    uint32_t S = block_scan_incl(v);
    if (S >= krem && (S - v) < krem) {
      uint32_t cum = S - v;
      for (int j = 0; j < 8; ++j) {
        cum += bl[j];
        if (cum >= krem) { fsel_bin = base - j; fsel_hd = bl[j]; fsel_above = cum - bl[j]; break; }
      }
    }
    __syncthreads();
  }
  uint64_t prefix = (uint64_t)fsel_bin;
  krem = kK - fsel_above;
  uint32_t Sge = (kK - krem) + fsel_hd;
  int shift = 37;
  __syncthreads();

  // refine the floor until the candidate set fits in LDS (terminates: the
  // last pass pins the full 48-bit key -> Sge == kK).
  while (Sge > kCap) {
    int w = (shift > 8) ? 8 : shift;
    int ns = shift - w, bins = 1 << w, hs = shift;
    for (int i = tid; i < bins; i += 256) hist[i] = 0;
    __syncthreads();
    for (int n = tid; n < kN; n += 256) {
      float s = cl[(size_t)n * kC] * ct[n];
      uint64_t k = make_key(s, n);
      if ((k >> hs) == prefix) atomicAdd(&hist[(uint32_t)(k >> ns) & (bins - 1)], 1u);
    }
    __syncthreads();
    uint32_t v = (tid < bins) ? hist[bins - 1 - tid] : 0;
    uint32_t S = block_scan_incl(v);
    if (v && S >= krem && (S - v) < krem) { fsel_bin = bins - 1 - tid; fsel_hd = v; fsel_above = S - v; }
    __syncthreads();
    prefix = (prefix << w) | (uint32_t)fsel_bin;
    krem -= fsel_above;
    Sge = (kK - krem) + fsel_hd;
    shift = ns;
    __syncthreads();
  }

  // gather all keys >= floor (exactly Sge of them, Sge <= kCap)
  uint64_t L = prefix << shift;
  if (tid == 0) fcnt = 0;
  __syncthreads();
  for (int n = tid; n < kN; n += 256) {
    float s = cl[(size_t)n * kC] * ct[n];
    uint64_t k = make_key(s, n);
    if (k >= L) {
      uint32_t p = atomicAdd(&fcnt, 1u);
      if (p < kCap) keybuf[p] = k;
    }
  }
  __syncthreads();
  int Scnt = (int)fcnt;
  return Scnt > kCap ? kCap : Scnt;
}

// ---- 2-pass exact top-K over a small global array (final top-100 only) ----
__device__ void select_topk(const float4* __restrict__ s4, int n4, int K,
                            uint32_t* hist, uint64_t* keybuf, uint64_t* cbuf) {
  __shared__ int sel_bin;
  __shared__ uint32_t sel_hd, sel_above, sel_k, cnt;
  int tid = threadIdx.x;

  for (int i = tid; i < kBins1; i += 256) hist[i] = 0;
  __syncthreads();
  for (int i = tid; i < n4; i += 256) {
    float4 f = s4[i];
    atomicAdd(&hist[__float_as_uint(f.x) >> 21], 1u);
    atomicAdd(&hist[__float_as_uint(f.y) >> 21], 1u);
    atomicAdd(&hist[__float_as_uint(f.z) >> 21], 1u);
    atomicAdd(&hist[__float_as_uint(f.w) >> 21], 1u);
  }
  __syncthreads();
  uint32_t krem = (uint32_t)K;
  {
    uint32_t bl[8], v = 0;
    int base = kBins1 - 1 - 8 * tid;
    for (int j = 0; j < 8; ++j) { bl[j] = hist[base - j]; v += bl[j]; }
    uint32_t S = block_scan_incl(v);
    if (S >= krem && (S - v) < krem) {
      uint32_t cum = S - v;
      for (int j = 0; j < 8; ++j) {
        cum += bl[j];
        if (cum >= krem) { sel_bin = base - j; sel_hd = bl[j]; sel_above = cum - bl[j]; break; }
      }
    }
    __syncthreads();
  }
  uint64_t prefix = (uint64_t)sel_bin;
  krem = (uint32_t)K - sel_above;
  uint32_t Sge = ((uint32_t)K - krem) + sel_hd;
  int shift = 37;
  __syncthreads();

  while (Sge > kCap) {
    int w = (shift > 8) ? 8 : shift;
    int ns = shift - w, bins = 1 << w, hs = shift;
    for (int i = tid; i < bins; i += 256) hist[i] = 0;
    __syncthreads();
    for (int i = tid; i < n4; i += 256) {
      float4 f = s4[i];
      int n = i * 4;
      float sv[4] = {f.x, f.y, f.z, f.w};
      for (int j = 0; j < 4; ++j) {
        uint64_t k = make_key(sv[j], n + j);
        if ((k >> hs) == prefix)
          atomicAdd(&hist[(uint32_t)(k >> ns) & (bins - 1)], 1u);
      }
    }
    __syncthreads();
    uint32_t v = (tid < bins) ? hist[bins - 1 - tid] : 0;
    uint32_t S = block_scan_incl(v);
    if (v && S >= krem && (S - v) < krem) {
      sel_bin = bins - 1 - tid; sel_hd = v; sel_above = S - v;
    }
    __syncthreads();
    prefix = (prefix << w) | (uint32_t)sel_bin;
    krem -= sel_above;
    Sge = ((uint32_t)K - krem) + sel_hd;
    shift = ns;
    __syncthreads();
  }

  uint64_t L = prefix << shift;
  if (tid == 0) cnt = 0;
  __syncthreads();
  for (int i = tid; i < n4; i += 256) {
    float4 f = s4[i];
    int n = i * 4;
    float sv[4] = {f.x, f.y, f.z, f.w};
    for (int j = 0; j < 4; ++j) {
      uint64_t k = make_key(sv[j], n + j);
      if (k >= L) {
        uint32_t p = atomicAdd(&cnt, 1u);
        if (p < kCap) keybuf[p] = k;
      }
    }
  }
  __syncthreads();
  int Scnt = (int)cnt;
  if (Scnt > kCap) Scnt = kCap;

  uint64_t thr48 = 0;
  uint32_t krem2 = (uint32_t)K;
  for (int sh = 40; sh >= 0; sh -= 8) {
    if (tid < 256) hist[tid] = 0;
    __syncthreads();
    uint64_t pmask = (sh == 40) ? 0ull : (~0ull << (sh + 8));
    for (int i = tid; i < Scnt; i += 256) {
      uint64_t k = keybuf[i];
      if ((k & pmask) == thr48)
        atomicAdd(&hist[(uint32_t)(k >> sh) & 0xFFu], 1u);
    }
    __syncthreads();
    uint32_t v = hist[255 - tid];
    uint32_t S = block_scan_incl(v);
    if (S >= krem2 && (S - v) < krem2) {
      sel_bin = 255 - tid;
      sel_k = krem2 - (S - v);
    }
    __syncthreads();
    thr48 |= ((uint64_t)sel_bin) << sh;
    krem2 = sel_k;
    __syncthreads();
  }

  if (tid == 0) cnt = 0;
  __syncthreads();
  for (int i = tid; i < Scnt; i += 256) {
    uint64_t k = keybuf[i];
    if (k >= thr48) {
      uint32_t p = atomicAdd(&cnt, 1u);
      if (p < (uint32_t)K) cbuf[p] = k;
    }
  }
  __syncthreads();
}

// ---- zero the per-row candidate counters (d_ws is re-poisoned per call) ----
__global__ __launch_bounds__(256) void zero_cnt_kernel(uint32_t* __restrict__ gcnt) {
  int i = blockIdx.x * 256 + threadIdx.x;
  if (i < kRows) gcnt[i] = 0;
}

// ---- fused score (clf*ctr) + threshold-prune append to per-(b,c) lists ----
__global__ __launch_bounds__(256) void score_scan_kernel(
    const float* __restrict__ clfs, const float* __restrict__ ctrs,
    uint32_t* __restrict__ gcnt, uint64_t* __restrict__ glist) {
  int b = blockIdx.y;
  int n0 = blockIdx.x * 64;        // kN = 64*341 exact
  int tid = threadIdx.x;
  __shared__ float ct[64];
  if (tid < 64) ct[tid] = ctrs[(size_t)b * kN + n0 + tid];
  __syncthreads();
  const float4* src = (const float4*)(clfs + ((size_t)b * kN + n0) * kC);
  for (int e = tid; e < 64 * kC / 4; e += 256) {    // 1280 float4 per block
    float4 v = src[e];
    int a = e / 20;                // anchor within tile (kC/4 = 20)
    int c0 = (e % 20) * 4;         // class of component .x (never wraps: 4|80)
    float cv = ct[a];
    int n = n0 + a;
    float s0 = v.x * cv, s1 = v.y * cv, s2 = v.z * cv, s3 = v.w * cv;
    if (s0 > kThr) {
      int row = b * kC + c0;
      uint32_t p = atomicAdd(&gcnt[row], 1u);
      if (p < kCap) glist[(size_t)row * kCap + p] = make_key(s0, n);
    }
    if (s1 > kThr) {
      int row = b * kC + c0 + 1;
      uint32_t p = atomicAdd(&gcnt[row], 1u);
      if (p < kCap) glist[(size_t)row * kCap + p] = make_key(s1, n);
    }
    if (s2 > kThr) {
      int row = b * kC + c0 + 2;
      uint32_t p = atomicAdd(&gcnt[row], 1u);
      if (p < kCap) glist[(size_t)row * kCap + p] = make_key(s2, n);
    }
    if (s3 > kThr) {
      int row = b * kC + c0 + 3;
      uint32_t p = atomicAdd(&gcnt[row], 1u);
      if (p < kCap) glist[(size_t)row * kCap + p] = make_key(s3, n);
    }
  }
}

// ---- per-(batch,class): candidate list -> exact top-256 -> NMS -> top-100 ----
__global__ __launch_bounds__(256) void nms_class_kernel(
    const uint32_t* __restrict__ gcnt, const uint64_t* __restrict__ glist,
    const float* __restrict__ clfs, const float* __restrict__ ctrs,
    const float* __restrict__ regs,
    float* __restrict__ cls_boxes, float* __restrict__ cls_scores) {
  int row = blockIdx.x;
  int b = row / kC, c = row % kC;
  int tid = threadIdx.x;
  int lane = tid & 63, wave = tid >> 6;

  __shared__ union {
    uint32_t hist[kBins1];                 // select phase (incl. fallback)
    uint64_t supm[kK][4];                  // NMS suppression bit-matrix (8 KB)
  } hu;
  __shared__ uint64_t keybuf[kCap];        // 12 KB
  __shared__ uint64_t cbuf[kK];            // exact top-256 (unsorted)
  __shared__ uint64_t skey[kK];            // sorted top-256 keys
  __shared__ float by1[kK], bx1[kK], by2[kK], bx2[kK], barea[kK];
  __shared__ uint64_t kinit[4];            // initial keep mask (valid bits)
  __shared__ int sel_bin;
  __shared__ uint32_t sel_k, ccnt;

  // fast path: pruned list holds a superset of the top-256
  // (cnt >= kK  ==> the 256th-largest score > kThr ==> all top-256 in list;
  //  cnt <= kCap ==> nothing was dropped by the capacity guard)
  uint32_t cnt = gcnt[row];
  int Scnt;
  if (cnt >= (uint32_t)kK && cnt <= (uint32_t)kCap) {
    const uint64_t* gl = glist + (size_t)row * kCap;
    for (int i = tid; i < (int)cnt; i += 256) keybuf[i] = gl[i];
    Scnt = (int)cnt;
    __syncthreads();
  } else {
    Scnt = fallback_gather(clfs, ctrs, b, c, hu.hist, keybuf);
  }

  // in-LDS exact radix select: 48-bit key of the 256th largest
  uint64_t thr48 = 0;
  uint32_t krem2 = kK;
  for (int sh = 40; sh >= 0; sh -= 8) {
    if (tid < 256) hu.hist[tid] = 0;
    __syncthreads();
    uint64_t pmask = (sh == 40) ? 0ull : (~0ull << (sh + 8));
    for (int i = tid; i < Scnt; i += 256) {
      uint64_t k = keybuf[i];
      if ((k & pmask) == thr48)
        atomicAdd(&hu.hist[(uint32_t)(k >> sh) & 0xFFu], 1u);
    }
    __syncthreads();
    uint32_t v = hu.hist[255 - tid];
    uint32_t S = block_scan_incl(v);
    if (S >= krem2 && (S - v) < krem2) {
      sel_bin = 255 - tid;
      sel_k = krem2 - (S - v);
    }
    __syncthreads();
    thr48 |= ((uint64_t)sel_bin) << sh;
    krem2 = sel_k;
    __syncthreads();
  }

  // compact the exact 256 qualifiers (unsorted), then rank-sort
  if (tid == 0) ccnt = 0;
  __syncthreads();
  for (int i = tid; i < Scnt; i += 256) {
    uint64_t k = keybuf[i];
    if (k >= thr48) {
      uint32_t p = atomicAdd(&ccnt, 1u);
      if (p < kK) cbuf[p] = k;               // exactly kK land (keys unique)
    }
  }
  __syncthreads();
  uint64_t myk = cbuf[tid];
  {
    int r = 0;
    for (int i = 0; i < kK; ++i) r += (cbuf[i] > myk);
    skey[r] = myk;
  }
  __syncthreads();

  // decode my candidate's box directly from regs (fused decode)
  myk = skey[tid];
  int n = 0xFFFF - (int)(myk & 0xFFFF);
  float sc_v = __uint_as_float((uint32_t)(myk >> 16));
  int off, hl;
  float sf;
  if (n < 16384)      { off = 0;     hl = 7; sf = 8.f;   }
  else if (n < 20480) { off = 16384; hl = 6; sf = 16.f;  }
  else if (n < 21504) { off = 20480; hl = 5; sf = 32.f;  }
  else if (n < 21760) { off = 21504; hl = 4; sf = 64.f;  }
  else                { off = 21760; hl = 3; sf = 128.f; }
  int kk = n - off;
  // meshgrid(h, w) with 'xy' indexing -> gy = k % H, gx = k / H
  float gx = (float)(kk >> hl);
  float gy = (float)(kk & ((1 << hl) - 1));
  const float4 r = ((const float4*)regs)[(size_t)b * kN + n];
  float my_y1 = (gy - r.z) * sf;
  float my_x1 = (gx - r.x) * sf;
  float my_y2 = (gy + r.w) * sf;
  float my_x2 = (gx + r.y) * sf;
  float my_a = (my_y2 - my_y1) * (my_x2 - my_x1);
  by1[tid] = my_y1; bx1[tid] = my_x1; by2[tid] = my_y2; bx2[tid] = my_x2;
  barea[tid] = my_a;
  unsigned long long vm = __ballot(sc_v > 0.05f);   // valid = top_s > CONF_THR
  if (lane == 0) kinit[wave] = vm;
  __syncthreads();   // SoA boxes + kinit visible; hu.hist no longer needed

  // phase A: suppression rows -- thread i computes bits over j > i.
  // Exact reference arithmetic: fmax/fmin symmetric; area_j+area_i commutes;
  // contract(off) keeps inter separate from the union subtract; the double
  // compare is exactly RN(inter/unc) > 0.5 (see kIouC note).
  for (int w = 0; w < 4; ++w) {
    uint64_t bits = 0;
    int j0 = w << 6;
    int js = (tid + 1 > j0) ? tid + 1 : j0;
    int j1 = j0 + 64;
    for (int j = js; j < j1; ++j) {
      float yy1 = fmaxf(by1[j], my_y1);
      float yy2 = fminf(by2[j], my_y2);
      float xx1 = fmaxf(bx1[j], my_x1);
      float xx2 = fminf(bx2[j], my_x2);
      float ih = fmaxf(yy2 - yy1, 0.0f);
      float iw = fmaxf(xx2 - xx1, 0.0f);
      float inter = ih * iw;
      float un = (barea[j] + my_a) - inter;
      float unc = fmaxf(un, 1e-8f);
      bits |= ((uint64_t)((double)inter > kIouC * (double)unc)) << (j - j0);
    }
    hu.supm[tid][w] = bits;
  }
  __syncthreads();

  // phase B: greedy resolution, redundantly per wave (no barriers).
  uint64_t kw = (lane < 4) ? kinit[lane] : 0ull;
  for (int i = 0; i < kK; ++i) {
    uint64_t wsrc = __shfl(kw, i >> 6);
    if ((wsrc >> (i & 63)) & 1ull) {       // wave-uniform branch
      if (lane < 4) kw &= ~hu.supm[i][lane];
    }
  }
  uint32_t myp = (uint32_t)__popcll(kw);
  uint64_t ww = __shfl(kw, wave);          // final keep word for my tid
  bool keptf = (ww >> lane) & 1ull;
  int kept_total = (int)(__shfl(myp, 0) + __shfl(myp, 1) +
                         __shfl(myp, 2) + __shfl(myp, 3));
  int kept_before = (int)__popcll(ww & ((1ull << lane) - 1ull));
  for (int w = 0; w < wave; ++w) kept_before += (int)__shfl(myp, w);

  // stable top-100 of kept scores: kept candidates are already in descending
  // (score,-index) order; zero slots tie-break by position. Final order =
  // kept (tid order) then suppressed (tid order) == reference stable top_k.
  int rank2 = keptf ? kept_before : (kept_total + tid - kept_before);
  if (rank2 < kMaxPC) {
    float ks = keptf ? sc_v : 0.0f;
    size_t obase = ((size_t)row) * kMaxPC + rank2;
    cls_scores[obase] = ks;
    float* ob = cls_boxes + obase * 4;
    ob[0] = my_y1; ob[1] = my_x1; ob[2] = my_y2; ob[3] = my_x2;
  }
}

// ---- per-batch: stable top-100 over 80*100 entries, write final outputs ----
__global__ __launch_bounds__(256) void final_topk_kernel(
    const float* __restrict__ cls_scores, const float* __restrict__ cls_boxes,
    float* __restrict__ out) {
  int b = blockIdx.x;
  int tid = threadIdx.x;
  const int M = kC * kMaxPC;  // 8000
  const float* s = cls_scores + (size_t)b * M;

  __shared__ uint32_t hist[kBins1];
  __shared__ uint64_t keybuf[kCap];
  __shared__ uint64_t cbuf[kMaxDet];
  select_topk((const float4*)s, M / 4, kMaxDet, hist, keybuf, cbuf);

  if (tid < kMaxDet) {
    uint64_t myk = cbuf[tid];
    int rank = 0;
    for (int i = 0; i < kMaxDet; ++i) rank += (cbuf[i] > myk);
    float sv = __uint_as_float((uint32_t)(myk >> 16));
    int f = 0xFFFF - (int)(myk & 0xFFFF);
    int cls = f / 100;
    const float* bp = cls_boxes + ((size_t)b * M + f) * 4;
    float m = (sv > 0.0f) ? 1.0f : 0.0f;   // fin_b zeroed where fin_s <= 0
    float* ob = out + ((size_t)b * kMaxDet + rank) * 4;
    ob[0] = bp[0] * m; ob[1] = bp[1] * m; ob[2] = bp[2] * m; ob[3] = bp[3] * m;
    out[(size_t)kB * kMaxDet * 4 + (size_t)b * kMaxDet + rank] = (float)cls;
    out[(size_t)kB * kMaxDet * 5 + (size_t)b * kMaxDet + rank] = sv;
  }
}

extern "C" void kernel_launch(void* const* d_in, const int* in_sizes, int n_in,
                              void* d_out, int out_size, void* d_ws, size_t ws_size,
                              hipStream_t stream) {
  (void)in_sizes; (void)n_in; (void)out_size;
  const float* regs = (const float*)d_in[0];
  const float* ctrs = (const float*)d_in[1];
  const float* clfs = (const float*)d_in[2];
  float* out = (float*)d_out;

  const size_t glB  = (size_t)kRows * kCap * sizeof(uint64_t);      // 15.7 MB
  const size_t cbB  = (size_t)kRows * kMaxPC * 4 * sizeof(float);   // 2.0 MB
  const size_t csB  = (size_t)kRows * kMaxPC * sizeof(float);       // 0.5 MB
  const size_t cntB = 8192;                                          // 1280 u32, padded
  if (ws_size < glB + cbB + csB + cntB) return;  // fail visibly, no OOB

  char* p = (char*)d_ws;
  uint64_t* glist   = (uint64_t*)p; p += glB;
  float* cls_boxes  = (float*)p;    p += cbB;
  float* cls_scores = (float*)p;    p += csB;
  uint32_t* gcnt    = (uint32_t*)p;

  zero_cnt_kernel<<<(kRows + 255) / 256, 256, 0, stream>>>(gcnt);
  score_scan_kernel<<<dim3(kN / 64, kB), 256, 0, stream>>>(clfs, ctrs, gcnt, glist);
  nms_class_kernel<<<kRows, 256, 0, stream>>>(gcnt, glist, clfs, ctrs, regs,
                                              cls_boxes, cls_scores);
  final_topk_kernel<<<kB, 256, 0, stream>>>(cls_scores, cls_boxes, out);
}

// Round 6
// 345.103 us; speedup vs baseline: 2.1139x; 2.1139x over previous
//
#include <hip/hip_runtime.h>
#include <stdint.h>

// Keep every f32 op un-fused: the reference (numpy/jax f32) computes
// inter = ih*iw; union = a_i + a_j - inter as separate rounded ops. With
// HIP's default -ffp-contract=fast the subtract would fuse into an FMA and
// could flip borderline iou > 0.5 decisions -> wrong box selected.
#pragma clang fp contract(off)

namespace {
constexpr int kN = 21824;      // 128^2 + 64^2 + 32^2 + 16^2 + 8^2
constexpr int kB = 16;
constexpr int kC = 80;
constexpr int kK = 256;        // K_CAND
constexpr int kMaxPC = 100;
constexpr int kMaxDet = 100;
constexpr int kBins1 = 2048;   // fallback histogram bins (top 11 score bits)
constexpr int kCap = 1536;     // per-row candidate capacity (u64 keys)
constexpr int kRows = kB * kC; // 1280
constexpr int kTiles = kN / 64;            // 341
constexpr int kTPB = 6;                    // tiles (of 64 anchors) per scan block
constexpr int kGScan = (kTiles + kTPB - 1) / kTPB;   // 57 blocks per batch
constexpr int kLCap = 64;      // per-class per-block LDS list capacity
// Prune floor for the fast path. For this benchmark's product-of-uniforms
// scores, #(s > 0.72) per row ~ mean 950, sd 30 -> inside [kK, kCap] with
// ~10-sigma margin; per-block per-class count ~ mean 17, sd 4 -> < kLCap
// with >10-sigma margin. ANY violation routes to the exact fallback
// (overflow marks the row counter > kCap), so this is a speed heuristic
// only, never a correctness assumption.
constexpr float kThr = 0.72f;
// Exact iou>0.5 without division: RN(inter/unc) > 0.5  <=>  inter > (0.5+2^-25)*unc.
// (0.5+2^-25)*unc is exact in double (25b x 24b mantissa <= 49b); the tie at
// q = 0.5+2^-25 rounds-to-even down to 0.5, so the strict > matches exactly.
constexpr double kIouC = 0x1.000001p-1;   // 0.5 + 2^-25
}

// ---- 48-bit sort key: score bits (high 32) | (0xFFFF - index) (low 16) ----
// scores are >= 0 so the raw f32 bit pattern is order-monotone; the index
// complement reproduces jax top_k's stable tie-break (lower index wins).
__device__ __forceinline__ uint64_t make_key(float s, int n) {
  return ((uint64_t)__float_as_uint(s) << 16) | (uint32_t)(0xFFFF - n);
}

// Block-wide (256 threads) inclusive prefix scan.
__device__ uint32_t block_scan_incl(uint32_t val) {
  __shared__ uint32_t wsum[4];
  int lane = threadIdx.x & 63;
  int wave = threadIdx.x >> 6;
  for (int d = 1; d < 64; d <<= 1) {
    uint32_t t = __shfl_up(val, (unsigned)d, 64);
    if (lane >= d) val += t;
  }
  if (lane == 63) wsum[wave] = val;
  __syncthreads();
  uint32_t off = 0;
  for (int w = 0; w < wave; ++w) off += wsum[w];
  __syncthreads();
  return val + off;
}

// ---- exact fallback: gather a <=kCap superset of the top-256 keys of one
// class column directly from clfs/ctrs (strided reads; slow but bit-exact).
__device__ int fallback_gather(const float* __restrict__ clfs,
                               const float* __restrict__ ctrs, int b, int c,
                               uint32_t* hist, uint64_t* keybuf) {
  __shared__ int fsel_bin;
  __shared__ uint32_t fsel_hd, fsel_above, fcnt;
  int tid = threadIdx.x;
  const float* cl = clfs + (size_t)b * kN * kC + c;
  const float* ct = ctrs + (size_t)b * kN;

  // pass 1: 2048-bin histogram over score bits >> 21 (= key bits [37..48))
  for (int i = tid; i < kBins1; i += 256) hist[i] = 0;
  __syncthreads();
  for (int n = tid; n < kN; n += 256) {
    float s = cl[(size_t)n * kC] * ct[n];
    atomicAdd(&hist[__float_as_uint(s) >> 21], 1u);
  }
  __syncthreads();
  uint32_t krem = kK;
  {
    uint32_t bl[8], v = 0;
    int base = kBins1 - 1 - 8 * tid;
    for (int j = 0; j < 8; ++j) { bl[j] = hist[base - j]; v += bl[j]; }
    uint32_t S = block_scan_incl(v);
    if (S >= krem && (S - v) < krem) {
      uint32_t cum = S - v;
      for (int j = 0; j < 8; ++j) {
        cum += bl[j];
        if (cum >= krem) { fsel_bin = base - j; fsel_hd = bl[j]; fsel_above = cum - bl[j]; break; }
      }
    }
    __syncthreads();
  }
  uint64_t prefix = (uint64_t)fsel_bin;
  krem = kK - fsel_above;
  uint32_t Sge = (kK - krem) + fsel_hd;
  int shift = 37;
  __syncthreads();

  // refine the floor until the candidate set fits in LDS (terminates: the
  // last pass pins the full 48-bit key -> Sge == kK).
  while (Sge > kCap) {
    int w = (shift > 8) ? 8 : shift;
    int ns = shift - w, bins = 1 << w, hs = shift;
    for (int i = tid; i < bins; i += 256) hist[i] = 0;
    __syncthreads();
    for (int n = tid; n < kN; n += 256) {
      float s = cl[(size_t)n * kC] * ct[n];
      uint64_t k = make_key(s, n);
      if ((k >> hs) == prefix) atomicAdd(&hist[(uint32_t)(k >> ns) & (bins - 1)], 1u);
    }
    __syncthreads();
    uint32_t v = (tid < bins) ? hist[bins - 1 - tid] : 0;
    uint32_t S = block_scan_incl(v);
    if (v && S >= krem && (S - v) < krem) { fsel_bin = bins - 1 - tid; fsel_hd = v; fsel_above = S - v; }
    __syncthreads();
    prefix = (prefix << w) | (uint32_t)fsel_bin;
    krem -= fsel_above;
    Sge = (kK - krem) + fsel_hd;
    shift = ns;
    __syncthreads();
  }

  // gather all keys >= floor (exactly Sge of them, Sge <= kCap)
  uint64_t L = prefix << shift;
  if (tid == 0) fcnt = 0;
  __syncthreads();
  for (int n = tid; n < kN; n += 256) {
    float s = cl[(size_t)n * kC] * ct[n];
    uint64_t k = make_key(s, n);
    if (k >= L) {
      uint32_t p = atomicAdd(&fcnt, 1u);
      if (p < kCap) keybuf[p] = k;
    }
  }
  __syncthreads();
  int Scnt = (int)fcnt;
  return Scnt > kCap ? kCap : Scnt;
}

// ---- 2-pass exact top-K over a small global array (final top-100 only) ----
__device__ void select_topk(const float4* __restrict__ s4, int n4, int K,
                            uint32_t* hist, uint64_t* keybuf, uint64_t* cbuf) {
  __shared__ int sel_bin;
  __shared__ uint32_t sel_hd, sel_above, sel_k, cnt;
  int tid = threadIdx.x;

  for (int i = tid; i < kBins1; i += 256) hist[i] = 0;
  __syncthreads();
  for (int i = tid; i < n4; i += 256) {
    float4 f = s4[i];
    atomicAdd(&hist[__float_as_uint(f.x) >> 21], 1u);
    atomicAdd(&hist[__float_as_uint(f.y) >> 21], 1u);
    atomicAdd(&hist[__float_as_uint(f.z) >> 21], 1u);
    atomicAdd(&hist[__float_as_uint(f.w) >> 21], 1u);
  }
  __syncthreads();
  uint32_t krem = (uint32_t)K;
  {
    uint32_t bl[8], v = 0;
    int base = kBins1 - 1 - 8 * tid;
    for (int j = 0; j < 8; ++j) { bl[j] = hist[base - j]; v += bl[j]; }
    uint32_t S = block_scan_incl(v);
    if (S >= krem && (S - v) < krem) {
      uint32_t cum = S - v;
      for (int j = 0; j < 8; ++j) {
        cum += bl[j];
        if (cum >= krem) { sel_bin = base - j; sel_hd = bl[j]; sel_above = cum - bl[j]; break; }
      }
    }
    __syncthreads();
  }
  uint64_t prefix = (uint64_t)sel_bin;
  krem = (uint32_t)K - sel_above;
  uint32_t Sge = ((uint32_t)K - krem) + sel_hd;
  int shift = 37;
  __syncthreads();

  while (Sge > kCap) {
    int w = (shift > 8) ? 8 : shift;
    int ns = shift - w, bins = 1 << w, hs = shift;
    for (int i = tid; i < bins; i += 256) hist[i] = 0;
    __syncthreads();
    for (int i = tid; i < n4; i += 256) {
      float4 f = s4[i];
      int n = i * 4;
      float sv[4] = {f.x, f.y, f.z, f.w};
      for (int j = 0; j < 4; ++j) {
        uint64_t k = make_key(sv[j], n + j);
        if ((k >> hs) == prefix)
          atomicAdd(&hist[(uint32_t)(k >> ns) & (bins - 1)], 1u);
      }
    }
    __syncthreads();
    uint32_t v = (tid < bins) ? hist[bins - 1 - tid] : 0;
    uint32_t S = block_scan_incl(v);
    if (v && S >= krem && (S - v) < krem) {
      sel_bin = bins - 1 - tid; sel_hd = v; sel_above = S - v;
    }
    __syncthreads();
    prefix = (prefix << w) | (uint32_t)sel_bin;
    krem -= sel_above;
    Sge = ((uint32_t)K - krem) + sel_hd;
    shift = ns;
    __syncthreads();
  }

  uint64_t L = prefix << shift;
  if (tid == 0) cnt = 0;
  __syncthreads();
  for (int i = tid; i < n4; i += 256) {
    float4 f = s4[i];
    int n = i * 4;
    float sv[4] = {f.x, f.y, f.z, f.w};
    for (int j = 0; j < 4; ++j) {
      uint64_t k = make_key(sv[j], n + j);
      if (k >= L) {
        uint32_t p = atomicAdd(&cnt, 1u);
        if (p < kCap) keybuf[p] = k;
      }
    }
  }
  __syncthreads();
  int Scnt = (int)cnt;
  if (Scnt > kCap) Scnt = kCap;

  uint64_t thr48 = 0;
  uint32_t krem2 = (uint32_t)K;
  for (int sh = 40; sh >= 0; sh -= 8) {
    if (tid < 256) hist[tid] = 0;
    __syncthreads();
    uint64_t pmask = (sh == 40) ? 0ull : (~0ull << (sh + 8));
    for (int i = tid; i < Scnt; i += 256) {
      uint64_t k = keybuf[i];
      if ((k & pmask) == thr48)
        atomicAdd(&hist[(uint32_t)(k >> sh) & 0xFFu], 1u);
    }
    __syncthreads();
    uint32_t v = hist[255 - tid];
    uint32_t S = block_scan_incl(v);
    if (S >= krem2 && (S - v) < krem2) {
      sel_bin = 255 - tid;
      sel_k = krem2 - (S - v);
    }
    __syncthreads();
    thr48 |= ((uint64_t)sel_bin) << sh;
    krem2 = sel_k;
    __syncthreads();
  }

  if (tid == 0) cnt = 0;
  __syncthreads();
  for (int i = tid; i < Scnt; i += 256) {
    uint64_t k = keybuf[i];
    if (k >= thr48) {
      uint32_t p = atomicAdd(&cnt, 1u);
      if (p < (uint32_t)K) cbuf[p] = k;
    }
  }
  __syncthreads();
}

// ---- zero the per-row candidate counters (d_ws is re-poisoned per call) ----
__global__ __launch_bounds__(256) void zero_cnt_kernel(uint32_t* __restrict__ gcnt) {
  int i = blockIdx.x * 256 + threadIdx.x;
  if (i < kRows) gcnt[i] = 0;
}

// ---- fused score (clf*ctr) + prune, two-level append:
// per-class LDS lists first, then ONE global atomic + contiguous copy per
// class per block. Kills the atomic contention + write-allocate scatter that
// made the round-5 single-level version latency-bound.
__global__ __launch_bounds__(256) void score_scan_kernel(
    const float* __restrict__ clfs, const float* __restrict__ ctrs,
    uint32_t* __restrict__ gcnt, uint64_t* __restrict__ glist) {
  int b = blockIdx.y;
  int t0 = blockIdx.x * kTPB;
  int t1 = t0 + kTPB; if (t1 > kTiles) t1 = kTiles;
  int nbase = t0 * 64;
  int nanch = (t1 - t0) * 64;

  __shared__ uint64_t lbuf[kC][kLCap];   // 40 KB
  __shared__ uint32_t lcnt[kC];
  __shared__ float ct[kTPB * 64];
  int tid = threadIdx.x;
  for (int i = tid; i < kC; i += 256) lcnt[i] = 0;
  for (int i = tid; i < nanch; i += 256) ct[i] = ctrs[(size_t)b * kN + nbase + i];
  __syncthreads();

  const float4* src = (const float4*)(clfs + ((size_t)b * kN + nbase) * kC);
  int n4 = nanch * (kC / 4);             // 20 float4 per anchor
  for (int e = tid; e < n4; e += 256) {
    float4 v = src[e];
    int a = e / 20;                      // anchor within chunk
    int c0 = (e % 20) * 4;               // class of component .x (4 | 80)
    float cv = ct[a];
    int n = nbase + a;
    float sv[4] = {v.x * cv, v.y * cv, v.z * cv, v.w * cv};
    #pragma unroll
    for (int j = 0; j < 4; ++j) {
      if (sv[j] > kThr) {
        int c = c0 + j;
        uint32_t p = atomicAdd(&lcnt[c], 1u);
        if (p < kLCap) lbuf[c][p] = make_key(sv[j], n);
      }
    }
  }
  __syncthreads();

  // write-out: wave w owns classes [20w, 20w+20); one global atomic each,
  // then a contiguous 64-lane copy. LDS overflow -> push row count past kCap
  // so the NMS kernel takes the exact fallback path.
  int lane = tid & 63, wave = tid >> 6;
  for (int c = wave * 20; c < wave * 20 + 20; ++c) {
    uint32_t m = lcnt[c];                // uniform across the wave
    int row = b * kC + c;
    if (m > kLCap) {
      if (lane == 0) atomicAdd(&gcnt[row], (uint32_t)(kCap + 1));
      continue;
    }
    uint32_t base = 0;
    if (lane == 0 && m) base = atomicAdd(&gcnt[row], m);
    base = (uint32_t)__shfl((int)base, 0);
    for (uint32_t i = lane; i < m; i += 64) {
      uint32_t p = base + i;
      if (p < kCap) glist[(size_t)row * kCap + p] = lbuf[c][i];
    }
  }
}

// ---- per-(batch,class): candidate list -> exact top-256 -> NMS -> top-100 ----
__global__ __launch_bounds__(256) void nms_class_kernel(
    const uint32_t* __restrict__ gcnt, const uint64_t* __restrict__ glist,
    const float* __restrict__ clfs, const float* __restrict__ ctrs,
    const float* __restrict__ regs,
    float* __restrict__ cls_boxes, float* __restrict__ cls_scores) {
  int row = blockIdx.x;
  int b = row / kC, c = row % kC;
  int tid = threadIdx.x;
  int lane = tid & 63, wave = tid >> 6;

  __shared__ union {
    uint32_t hist[kBins1];                 // select phase (incl. fallback)
    uint64_t supm[kK][4];                  // NMS suppression bit-matrix (8 KB)
  } hu;
  __shared__ uint64_t keybuf[kCap];        // 12 KB
  __shared__ uint64_t cbuf[kK];            // exact top-256 (unsorted)
  __shared__ uint64_t skey[kK];            // sorted top-256 keys
  __shared__ float by1[kK], bx1[kK], by2[kK], bx2[kK], barea[kK];
  __shared__ uint64_t kinit[4];            // initial keep mask (valid bits)
  __shared__ int sel_bin;
  __shared__ uint32_t sel_k, ccnt;

  // fast path: pruned list holds a superset of the top-256
  // (cnt >= kK  ==> the 256th-largest score > kThr ==> all top-256 in list;
  //  cnt <= kCap ==> no block overflowed and no append was dropped)
  uint32_t cnt = gcnt[row];
  int Scnt;
  if (cnt >= (uint32_t)kK && cnt <= (uint32_t)kCap) {
    const uint64_t* gl = glist + (size_t)row * kCap;
    for (int i = tid; i < (int)cnt; i += 256) keybuf[i] = gl[i];
    Scnt = (int)cnt;
    __syncthreads();
  } else {
    Scnt = fallback_gather(clfs, ctrs, b, c, hu.hist, keybuf);
  }

  // in-LDS exact radix select: 48-bit key of the 256th largest
  uint64_t thr48 = 0;
  uint32_t krem2 = kK;
  for (int sh = 40; sh >= 0; sh -= 8) {
    if (tid < 256) hu.hist[tid] = 0;
    __syncthreads();
    uint64_t pmask = (sh == 40) ? 0ull : (~0ull << (sh + 8));
    for (int i = tid; i < Scnt; i += 256) {
      uint64_t k = keybuf[i];
      if ((k & pmask) == thr48)
        atomicAdd(&hu.hist[(uint32_t)(k >> sh) & 0xFFu], 1u);
    }
    __syncthreads();
    uint32_t v = hu.hist[255 - tid];
    uint32_t S = block_scan_incl(v);
    if (S >= krem2 && (S - v) < krem2) {
      sel_bin = 255 - tid;
      sel_k = krem2 - (S - v);
    }
    __syncthreads();
    thr48 |= ((uint64_t)sel_bin) << sh;
    krem2 = sel_k;
    __syncthreads();
  }

  // compact the exact 256 qualifiers (unsorted), then rank-sort
  if (tid == 0) ccnt = 0;
  __syncthreads();
  for (int i = tid; i < Scnt; i += 256) {
    uint64_t k = keybuf[i];
    if (k >= thr48) {
      uint32_t p = atomicAdd(&ccnt, 1u);
      if (p < kK) cbuf[p] = k;               // exactly kK land (keys unique)
    }
  }
  __syncthreads();
  uint64_t myk = cbuf[tid];
  {
    int r = 0;
    for (int i = 0; i < kK; ++i) r += (cbuf[i] > myk);
    skey[r] = myk;
  }
  __syncthreads();

  // decode my candidate's box directly from regs (fused decode)
  myk = skey[tid];
  int n = 0xFFFF - (int)(myk & 0xFFFF);
  float sc_v = __uint_as_float((uint32_t)(myk >> 16));
  int off, hl;
  float sf;
  if (n < 16384)      { off = 0;     hl = 7; sf = 8.f;   }
  else if (n < 20480) { off = 16384; hl = 6; sf = 16.f;  }
  else if (n < 21504) { off = 20480; hl = 5; sf = 32.f;  }
  else if (n < 21760) { off = 21504; hl = 4; sf = 64.f;  }
  else                { off = 21760; hl = 3; sf = 128.f; }
  int kk = n - off;
  // meshgrid(h, w) with 'xy' indexing -> gy = k % H, gx = k / H
  float gx = (float)(kk >> hl);
  float gy = (float)(kk & ((1 << hl) - 1));
  const float4 r = ((const float4*)regs)[(size_t)b * kN + n];
  float my_y1 = (gy - r.z) * sf;
  float my_x1 = (gx - r.x) * sf;
  float my_y2 = (gy + r.w) * sf;
  float my_x2 = (gx + r.y) * sf;
  float my_a = (my_y2 - my_y1) * (my_x2 - my_x1);
  by1[tid] = my_y1; bx1[tid] = my_x1; by2[tid] = my_y2; bx2[tid] = my_x2;
  barea[tid] = my_a;
  unsigned long long vm = __ballot(sc_v > 0.05f);   // valid = top_s > CONF_THR
  if (lane == 0) kinit[wave] = vm;
  __syncthreads();   // SoA boxes + kinit visible; hu.hist no longer needed

  // phase A: suppression rows -- thread i computes bits over j > i.
  // Exact reference arithmetic: fmax/fmin symmetric; area_j+area_i commutes;
  // contract(off) keeps inter separate from the union subtract; the double
  // compare is exactly RN(inter/unc) > 0.5 (see kIouC note).
  for (int w = 0; w < 4; ++w) {
    uint64_t bits = 0;
    int j0 = w << 6;
    int js = (tid + 1 > j0) ? tid + 1 : j0;
    int j1 = j0 + 64;
    for (int j = js; j < j1; ++j) {
      float yy1 = fmaxf(by1[j], my_y1);
      float yy2 = fminf(by2[j], my_y2);
      float xx1 = fmaxf(bx1[j], my_x1);
      float xx2 = fminf(bx2[j], my_x2);
      float ih = fmaxf(yy2 - yy1, 0.0f);
      float iw = fmaxf(xx2 - xx1, 0.0f);
      float inter = ih * iw;
      float un = (barea[j] + my_a) - inter;
      float unc = fmaxf(un, 1e-8f);
      bits |= ((uint64_t)((double)inter > kIouC * (double)unc)) << (j - j0);
    }
    hu.supm[tid][w] = bits;
  }
  __syncthreads();

  // phase B: greedy resolution, redundantly per wave (no barriers).
  uint64_t kw = (lane < 4) ? kinit[lane] : 0ull;
  for (int i = 0; i < kK; ++i) {
    uint64_t wsrc = __shfl(kw, i >> 6);
    if ((wsrc >> (i & 63)) & 1ull) {       // wave-uniform branch
      if (lane < 4) kw &= ~hu.supm[i][lane];
    }
  }
  uint32_t myp = (uint32_t)__popcll(kw);
  uint64_t ww = __shfl(kw, wave);          // final keep word for my tid
  bool keptf = (ww >> lane) & 1ull;
  int kept_total = (int)(__shfl(myp, 0) + __shfl(myp, 1) +
                         __shfl(myp, 2) + __shfl(myp, 3));
  int kept_before = (int)__popcll(ww & ((1ull << lane) - 1ull));
  for (int w = 0; w < wave; ++w) kept_before += (int)__shfl(myp, w);

  // stable top-100 of kept scores: kept candidates are already in descending
  // (score,-index) order; zero slots tie-break by position. Final order =
  // kept (tid order) then suppressed (tid order) == reference stable top_k.
  int rank2 = keptf ? kept_before : (kept_total + tid - kept_before);
  if (rank2 < kMaxPC) {
    float ks = keptf ? sc_v : 0.0f;
    size_t obase = ((size_t)row) * kMaxPC + rank2;
    cls_scores[obase] = ks;
    float* ob = cls_boxes + obase * 4;
    ob[0] = my_y1; ob[1] = my_x1; ob[2] = my_y2; ob[3] = my_x2;
  }
}

// ---- per-batch: stable top-100 over 80*100 entries, write final outputs ----
__global__ __launch_bounds__(256) void final_topk_kernel(
    const float* __restrict__ cls_scores, const float* __restrict__ cls_boxes,
    float* __restrict__ out) {
  int b = blockIdx.x;
  int tid = threadIdx.x;
  const int M = kC * kMaxPC;  // 8000
  const float* s = cls_scores + (size_t)b * M;

  __shared__ uint32_t hist[kBins1];
  __shared__ uint64_t keybuf[kCap];
  __shared__ uint64_t cbuf[kMaxDet];
  select_topk((const float4*)s, M / 4, kMaxDet, hist, keybuf, cbuf);

  if (tid < kMaxDet) {
    uint64_t myk = cbuf[tid];
    int rank = 0;
    for (int i = 0; i < kMaxDet; ++i) rank += (cbuf[i] > myk);
    float sv = __uint_as_float((uint32_t)(myk >> 16));
    int f = 0xFFFF - (int)(myk & 0xFFFF);
    int cls = f / 100;
    const float* bp = cls_boxes + ((size_t)b * M + f) * 4;
    float m = (sv > 0.0f) ? 1.0f : 0.0f;   // fin_b zeroed where fin_s <= 0
    float* ob = out + ((size_t)b * kMaxDet + rank) * 4;
    ob[0] = bp[0] * m; ob[1] = bp[1] * m; ob[2] = bp[2] * m; ob[3] = bp[3] * m;
    out[(size_t)kB * kMaxDet * 4 + (size_t)b * kMaxDet + rank] = (float)cls;
    out[(size_t)kB * kMaxDet * 5 + (size_t)b * kMaxDet + rank] = sv;
  }
}

extern "C" void kernel_launch(void* const* d_in, const int* in_sizes, int n_in,
                              void* d_out, int out_size, void* d_ws, size_t ws_size,
                              hipStream_t stream) {
  (void)in_sizes; (void)n_in; (void)out_size;
  const float* regs = (const float*)d_in[0];
  const float* ctrs = (const float*)d_in[1];
  const float* clfs = (const float*)d_in[2];
  float* out = (float*)d_out;

  const size_t glB  = (size_t)kRows * kCap * sizeof(uint64_t);      // 15.7 MB
  const size_t cbB  = (size_t)kRows * kMaxPC * 4 * sizeof(float);   // 2.0 MB
  const size_t csB  = (size_t)kRows * kMaxPC * sizeof(float);       // 0.5 MB
  const size_t cntB = 8192;                                          // 1280 u32, padded
  if (ws_size < glB + cbB + csB + cntB) return;  // fail visibly, no OOB

  char* p = (char*)d_ws;
  uint64_t* glist   = (uint64_t*)p; p += glB;
  float* cls_boxes  = (float*)p;    p += cbB;
  float* cls_scores = (float*)p;    p += csB;
  uint32_t* gcnt    = (uint32_t*)p;

  zero_cnt_kernel<<<(kRows + 255) / 256, 256, 0, stream>>>(gcnt);
  score_scan_kernel<<<dim3(kGScan, kB), 256, 0, stream>>>(clfs, ctrs, gcnt, glist);
  nms_class_kernel<<<kRows, 256, 0, stream>>>(gcnt, glist, clfs, ctrs, regs,
                                              cls_boxes, cls_scores);
  final_topk_kernel<<<kB, 256, 0, stream>>>(cls_scores, cls_boxes, out);
}

// Round 7
// 313.710 us; speedup vs baseline: 2.3255x; 1.1001x over previous
//
#include <hip/hip_runtime.h>
#include <stdint.h>

// Keep every f32 op un-fused: the reference (numpy/jax f32) computes
// inter = ih*iw; union = a_i + a_j - inter as separate rounded ops. With
// HIP's default -ffp-contract=fast the subtract would fuse into an FMA and
// could flip borderline iou > 0.5 decisions -> wrong box selected.
#pragma clang fp contract(off)

namespace {
constexpr int kN = 21824;      // 128^2 + 64^2 + 32^2 + 16^2 + 8^2
constexpr int kB = 16;
constexpr int kC = 80;
constexpr int kK = 256;        // K_CAND
constexpr int kMaxPC = 100;
constexpr int kMaxDet = 100;
constexpr int kBins1 = 2048;   // level-0 histogram bins (top 11 key bits)
constexpr int kCap = 1536;     // per-row global candidate capacity (u64 keys)
constexpr int kQCap = 320;     // post-refinement qualifier capacity (LDS)
constexpr int kRows = kB * kC; // 1280
constexpr int kTiles = kN / 64;            // 341
constexpr int kTPB = 6;                    // tiles (of 64 anchors) per scan block
constexpr int kGScan = (kTiles + kTPB - 1) / kTPB;   // 57 blocks per batch
constexpr int kLCap = 48;      // per-class per-block LDS list capacity
// Prune floor for the fast path. For this benchmark's product-of-uniforms
// scores, #(s > 0.72) per row ~ mean 950, sd 30 -> inside [kK, kCap] with
// ~10-sigma margin; per-block per-class count ~ mean 17, sd 4 -> < kLCap
// with ~7.8-sigma margin. ANY violation routes to the exact fallback
// (overflow marks the row counter > kCap), so this is a speed heuristic
// only, never a correctness assumption.
constexpr float kThr = 0.72f;
// Exact iou>0.5 without division: RN(inter/unc) > 0.5  <=>  inter > (0.5+2^-25)*unc.
// (0.5+2^-25)*unc is exact in double (25b x 24b mantissa <= 49b); the tie at
// q = 0.5+2^-25 rounds-to-even down to 0.5, so the strict > matches exactly.
constexpr double kIouC = 0x1.000001p-1;   // 0.5 + 2^-25
}

// ---- 48-bit sort key: score bits (high 32) | (0xFFFF - index) (low 16) ----
// scores are >= 0 so the raw f32 bit pattern is order-monotone; the index
// complement reproduces jax top_k's stable tie-break (lower index wins).
__device__ __forceinline__ uint64_t make_key(float s, int n) {
  return ((uint64_t)__float_as_uint(s) << 16) | (uint32_t)(0xFFFF - n);
}

// Block-wide (256 threads) inclusive prefix scan.
__device__ uint32_t block_scan_incl(uint32_t val) {
  __shared__ uint32_t wsum[4];
  int lane = threadIdx.x & 63;
  int wave = threadIdx.x >> 6;
  for (int d = 1; d < 64; d <<= 1) {
    uint32_t t = __shfl_up(val, (unsigned)d, 64);
    if (lane >= d) val += t;
  }
  if (lane == 63) wsum[wave] = val;
  __syncthreads();
  uint32_t off = 0;
  for (int w = 0; w < wave; ++w) off += wsum[w];
  __syncthreads();
  return val + off;
}

// ---- key sources for the refinement select ----
// Fast path: <=6 list keys per thread, held in registers.
struct RegSrc {
  uint64_t k[6];
  int cnt;                      // valid entries in k[]
  template <class F> __device__ void each(F f) const {
    #pragma unroll
    for (int j = 0; j < 6; ++j)
      if (j < cnt) f(k[j]);
  }
};
// Exact fallback: recompute scores from the strided class column each pass.
struct ColSrc {
  const float* cl;              // clfs + b*kN*kC + c  (stride kC)
  const float* ct;              // ctrs + b*kN
  template <class F> __device__ void each(F f) const {
    for (int n = threadIdx.x; n < kN; n += 256)
      f(make_key(cl[(size_t)n * kC] * ct[n], n));
  }
};

// ---- exact top-K floor via histogram refinement, then gather qualifiers.
// Level 0: 11-bit histogram over key bits [37..48). While the qualifier
// count exceeds cap, refine 8 more bits (terminates: the last level pins the
// full 48-bit key -> count == K). Returns Scnt (= #keys >= floor, K <= Scnt
// <= cap) with the qualifiers in cbuf[0..Scnt).
template <class Src>
__device__ int refine_gather(const Src& src, int K, int cap,
                             uint32_t* hist, uint64_t* cbuf) {
  __shared__ int sel_bin;
  __shared__ uint32_t sel_hd, sel_above, qcnt;
  int tid = threadIdx.x;

  for (int i = tid; i < kBins1; i += 256) hist[i] = 0;
  __syncthreads();
  src.each([&](uint64_t k) { atomicAdd(&hist[(uint32_t)(k >> 37)], 1u); });
  __syncthreads();
  uint32_t krem = (uint32_t)K;
  {
    uint32_t bl[8], v = 0;
    int base = kBins1 - 1 - 8 * tid;      // descending scan, 8 bins/thread
    for (int j = 0; j < 8; ++j) { bl[j] = hist[base - j]; v += bl[j]; }
    uint32_t S = block_scan_incl(v);
    if (S >= krem && (S - v) < krem) {
      uint32_t cum = S - v;
      for (int j = 0; j < 8; ++j) {
        cum += bl[j];
        if (cum >= krem) { sel_bin = base - j; sel_hd = bl[j]; sel_above = cum - bl[j]; break; }
      }
    }
    __syncthreads();
  }
  uint64_t prefix = (uint64_t)sel_bin;
  krem = (uint32_t)K - sel_above;
  uint32_t Sge = ((uint32_t)K - krem) + sel_hd;
  int shift = 37;
  __syncthreads();

  while (Sge > (uint32_t)cap) {
    int w = (shift > 8) ? 8 : shift;
    int ns = shift - w, bins = 1 << w, hs = shift;
    for (int i = tid; i < bins; i += 256) hist[i] = 0;
    __syncthreads();
    uint64_t pfx = prefix;
    src.each([&](uint64_t k) {
      if ((k >> hs) == pfx)
        atomicAdd(&hist[(uint32_t)(k >> ns) & (bins - 1)], 1u);
    });
    __syncthreads();
    uint32_t v = (tid < bins) ? hist[bins - 1 - tid] : 0;
    uint32_t S = block_scan_incl(v);
    if (v && S >= krem && (S - v) < krem) {
      sel_bin = bins - 1 - tid; sel_hd = v; sel_above = S - v;
    }
    __syncthreads();
    prefix = (prefix << w) | (uint32_t)sel_bin;
    krem -= sel_above;
    Sge = ((uint32_t)K - krem) + sel_hd;
    shift = ns;
    __syncthreads();
  }

  uint64_t L = prefix << shift;
  if (tid == 0) qcnt = 0;
  __syncthreads();
  src.each([&](uint64_t k) {
    if (k >= L) {
      uint32_t p = atomicAdd(&qcnt, 1u);
      if (p < (uint32_t)cap) cbuf[p] = k;
    }
  });
  __syncthreads();
  int Scnt = (int)qcnt;
  return Scnt > cap ? cap : Scnt;       // == Sge <= cap by construction
}

// ---- zero the per-row candidate counters (d_ws is re-poisoned per call) ----
__global__ __launch_bounds__(256) void zero_cnt_kernel(uint32_t* __restrict__ gcnt) {
  int i = blockIdx.x * 256 + threadIdx.x;
  if (i < kRows) gcnt[i] = 0;
}

// ---- fused score (clf*ctr) + prune, two-level append ----
__global__ __launch_bounds__(256) void score_scan_kernel(
    const float* __restrict__ clfs, const float* __restrict__ ctrs,
    uint32_t* __restrict__ gcnt, uint64_t* __restrict__ glist) {
  int b = blockIdx.y;
  int t0 = blockIdx.x * kTPB;
  int t1 = t0 + kTPB; if (t1 > kTiles) t1 = kTiles;
  int nbase = t0 * 64;
  int nanch = (t1 - t0) * 64;

  __shared__ uint64_t lbuf[kC][kLCap + 1]; // +1 pad: append banks spread
  __shared__ uint32_t lcnt[kC];
  __shared__ uint32_t gbase[kC];
  __shared__ float ct[kTPB * 64];
  int tid = threadIdx.x;
  for (int i = tid; i < kC; i += 256) lcnt[i] = 0;
  for (int i = tid; i < nanch; i += 256) ct[i] = ctrs[(size_t)b * kN + nbase + i];
  __syncthreads();

  const float4* src = (const float4*)(clfs + ((size_t)b * kN + nbase) * kC);
  int n4 = nanch * (kC / 4);             // 20 float4 per anchor
  #pragma unroll 4
  for (int e = tid; e < n4; e += 256) {
    float4 v = src[e];
    int a = e / 20;                      // anchor within chunk
    int c0 = (e % 20) * 4;               // class of component .x (4 | 80)
    float cv = ct[a];
    int n = nbase + a;
    float sv[4] = {v.x * cv, v.y * cv, v.z * cv, v.w * cv};
    #pragma unroll
    for (int j = 0; j < 4; ++j) {
      if (sv[j] > kThr) {
        int c = c0 + j;
        uint32_t p = atomicAdd(&lcnt[c], 1u);
        if (p < kLCap) lbuf[c][p] = make_key(sv[j], n);
      }
    }
  }
  __syncthreads();

  // parallel reservations: 80 concurrent global atomics (lanes), then copy.
  if (tid < kC) {
    uint32_t m = lcnt[tid];
    int row = b * kC + tid;
    if (m > kLCap) {                     // overflow -> force exact fallback
      atomicAdd(&gcnt[row], (uint32_t)(kCap + 1));
      gbase[tid] = 0xFFFFFFFFu;
    } else {
      gbase[tid] = m ? atomicAdd(&gcnt[row], m) : 0u;
    }
  }
  __syncthreads();

  int lane = tid & 63, wave = tid >> 6;
  for (int c = wave * 20; c < wave * 20 + 20; ++c) {
    uint32_t m = lcnt[c];
    uint32_t base = gbase[c];
    if (base == 0xFFFFFFFFu || m == 0) continue;
    if (m > kLCap) m = kLCap;
    int row = b * kC + c;
    for (uint32_t i = lane; i < m; i += 64) {
      uint32_t p = base + i;
      if (p < kCap) glist[(size_t)row * kCap + p] = lbuf[c][i];
    }
  }
}

// ---- per-(batch,class): list -> exact top-256 -> bit-matrix NMS -> top-100 ----
__global__ __launch_bounds__(256) void nms_class_kernel(
    const uint32_t* __restrict__ gcnt, const uint64_t* __restrict__ glist,
    const float* __restrict__ clfs, const float* __restrict__ ctrs,
    const float* __restrict__ regs,
    float* __restrict__ cls_boxes, float* __restrict__ cls_scores) {
  int row = blockIdx.x;
  int b = row / kC, c = row % kC;
  int tid = threadIdx.x;
  int lane = tid & 63, wave = tid >> 6;

  __shared__ union {
    uint32_t hist[kBins1];               // select phase (8 KB)
    uint64_t supm[kK][4];                // NMS suppression bit-matrix (8 KB)
  } hu;
  __shared__ uint64_t cbuf[kQCap];       // qualifiers (2.5 KB)
  __shared__ uint64_t skey[kK];          // sorted top-256 keys (2 KB)
  __shared__ float by1[kK], bx1[kK], by2[kK], bx2[kK], barea[kK];
  __shared__ uint64_t kinit[4];          // initial keep mask (valid bits)

  // fast path: pruned list holds a superset of the top-256
  // (cnt >= kK  ==> the 256th-largest score > kThr ==> all top-256 listed;
  //  cnt <= kCap ==> no block overflowed and no append was dropped)
  uint32_t cnt = gcnt[row];
  int Scnt;
  if (cnt >= (uint32_t)kK && cnt <= (uint32_t)kCap) {
    RegSrc rs; rs.cnt = 0;
    const uint64_t* gl = glist + (size_t)row * kCap;
    #pragma unroll
    for (int j = 0; j < 6; ++j) {
      int i = tid + j * 256;
      if (i < (int)cnt) { rs.k[j] = gl[i]; rs.cnt = j + 1; }
    }
    Scnt = refine_gather(rs, kK, kQCap, hu.hist, cbuf);
  } else {
    ColSrc cs{clfs + (size_t)b * kN * kC + c, ctrs + (size_t)b * kN};
    Scnt = refine_gather(cs, kK, kQCap, hu.hist, cbuf);
  }

  // rank-count sort: qualifiers with rank < 256 land sorted in skey
  for (int j = tid; j < Scnt; j += 256) {
    uint64_t kj = cbuf[j];
    int r = 0;
    for (int i = 0; i < Scnt; ++i) r += (cbuf[i] > kj);
    if (r < kK) skey[r] = kj;
  }
  __syncthreads();

  // decode my candidate's box directly from regs (fused decode)
  uint64_t myk = skey[tid];
  int n = 0xFFFF - (int)(myk & 0xFFFF);
  float sc_v = __uint_as_float((uint32_t)(myk >> 16));
  int off, hl;
  float sf;
  if (n < 16384)      { off = 0;     hl = 7; sf = 8.f;   }
  else if (n < 20480) { off = 16384; hl = 6; sf = 16.f;  }
  else if (n < 21504) { off = 20480; hl = 5; sf = 32.f;  }
  else if (n < 21760) { off = 21504; hl = 4; sf = 64.f;  }
  else                { off = 21760; hl = 3; sf = 128.f; }
  int kk = n - off;
  // meshgrid(h, w) with 'xy' indexing -> gy = k % H, gx = k / H
  float gx = (float)(kk >> hl);
  float gy = (float)(kk & ((1 << hl) - 1));
  const float4 r = ((const float4*)regs)[(size_t)b * kN + n];
  float my_y1 = (gy - r.z) * sf;
  float my_x1 = (gx - r.x) * sf;
  float my_y2 = (gy + r.w) * sf;
  float my_x2 = (gx + r.y) * sf;
  float my_a = (my_y2 - my_y1) * (my_x2 - my_x1);
  by1[tid] = my_y1; bx1[tid] = my_x1; by2[tid] = my_y2; bx2[tid] = my_x2;
  barea[tid] = my_a;
  unsigned long long vm = __ballot(sc_v > 0.05f);   // valid = top_s > CONF_THR
  if (lane == 0) kinit[wave] = vm;
  __syncthreads();   // SoA boxes + kinit visible; hu.hist no longer needed

  // phase A: suppression rows -- thread i computes bits over j > i.
  // Exact reference arithmetic: fmax/fmin symmetric; area_j+area_i commutes;
  // contract(off) keeps inter separate from the union subtract; the double
  // compare is exactly RN(inter/unc) > 0.5 (see kIouC note).
  for (int w = 0; w < 4; ++w) {
    uint64_t bits = 0;
    int j0 = w << 6;
    int js = (tid + 1 > j0) ? tid + 1 : j0;
    int j1 = j0 + 64;
    for (int j = js; j < j1; ++j) {
      float yy1 = fmaxf(by1[j], my_y1);
      float yy2 = fminf(by2[j], my_y2);
      float xx1 = fmaxf(bx1[j], my_x1);
      float xx2 = fminf(bx2[j], my_x2);
      float ih = fmaxf(yy2 - yy1, 0.0f);
      float iw = fmaxf(xx2 - xx1, 0.0f);
      float inter = ih * iw;
      float un = (barea[j] + my_a) - inter;
      float unc = fmaxf(un, 1e-8f);
      bits |= ((uint64_t)((double)inter > kIouC * (double)unc)) << (j - j0);
    }
    hu.supm[tid][w] = bits;
  }
  __syncthreads();

  // phase B: greedy resolution -- every thread redundantly holds the full
  // 256-bit keep mask in 4 VGPRs. Uniform branches, no shuffles, no barriers.
  // supm rows have bits only for j > i, so processed bits are never re-set.
  uint64_t kw0 = kinit[0], kw1 = kinit[1], kw2 = kinit[2], kw3 = kinit[3];
  #define RESOLVE_WORD(W, KW)                                        \
    for (int i2 = 0; i2 < 64; ++i2) {                                \
      if ((KW >> i2) & 1ull) {                                       \
        const uint64_t* sp = hu.supm[(W << 6) + i2];                 \
        kw0 &= ~sp[0]; kw1 &= ~sp[1]; kw2 &= ~sp[2]; kw3 &= ~sp[3];  \
      }                                                              \
    }
  RESOLVE_WORD(0, kw0)
  RESOLVE_WORD(1, kw1)
  RESOLVE_WORD(2, kw2)
  RESOLVE_WORD(3, kw3)
  #undef RESOLVE_WORD

  uint64_t ww = (wave == 0) ? kw0 : (wave == 1) ? kw1 : (wave == 2) ? kw2 : kw3;
  bool keptf = (ww >> lane) & 1ull;
  int kept_total = (int)(__popcll(kw0) + __popcll(kw1) +
                         __popcll(kw2) + __popcll(kw3));
  int kept_before = (int)__popcll(ww & ((1ull << lane) - 1ull));
  if (wave > 0) kept_before += (int)__popcll(kw0);
  if (wave > 1) kept_before += (int)__popcll(kw1);
  if (wave > 2) kept_before += (int)__popcll(kw2);

  // stable top-100 of kept scores: kept candidates are already in descending
  // (score,-index) order; zero slots tie-break by position. Final order =
  // kept (tid order) then suppressed (tid order) == reference stable top_k.
  int rank2 = keptf ? kept_before : (kept_total + tid - kept_before);
  if (rank2 < kMaxPC) {
    float ks = keptf ? sc_v : 0.0f;
    size_t obase = ((size_t)row) * kMaxPC + rank2;
    cls_scores[obase] = ks;
    float* ob = cls_boxes + obase * 4;
    ob[0] = my_y1; ob[1] = my_x1; ob[2] = my_y2; ob[3] = my_x2;
  }
}

// ---- per-batch: stable top-100 over 80*100 entries, write final outputs ----
// 8000 scores per block: load to registers (32/thread > needed? 8000/256 =
// 32 -> too many; stream from global, it's L2-hot) via ColSrc-like wrapper.
struct ArrSrc {
  const float* s;
  int count;
  template <class F> __device__ void each(F f) const {
    for (int i = threadIdx.x; i < count; i += 256) f(make_key(s[i], i));
  }
};

__global__ __launch_bounds__(256) void final_topk_kernel(
    const float* __restrict__ cls_scores, const float* __restrict__ cls_boxes,
    float* __restrict__ out) {
  int b = blockIdx.x;
  int tid = threadIdx.x;
  const int M = kC * kMaxPC;  // 8000
  __shared__ uint32_t hist[kBins1];
  __shared__ uint64_t cbuf[kQCap];

  ArrSrc as{cls_scores + (size_t)b * M, M};
  int Scnt = refine_gather(as, kMaxDet, kQCap, hist, cbuf);

  // rank-count: ranks < 100 are the final detections, sorted
  for (int j = tid; j < Scnt; j += 256) {
    uint64_t myk = cbuf[j];
    int rank = 0;
    for (int i = 0; i < Scnt; ++i) rank += (cbuf[i] > myk);
    if (rank < kMaxDet) {
      float sv = __uint_as_float((uint32_t)(myk >> 16));
      int f = 0xFFFF - (int)(myk & 0xFFFF);
      int cls = f / 100;
      const float* bp = cls_boxes + ((size_t)b * M + f) * 4;
      float m = (sv > 0.0f) ? 1.0f : 0.0f; // fin_b zeroed where fin_s <= 0
      float* ob = out + ((size_t)b * kMaxDet + rank) * 4;
      ob[0] = bp[0] * m; ob[1] = bp[1] * m; ob[2] = bp[2] * m; ob[3] = bp[3] * m;
      out[(size_t)kB * kMaxDet * 4 + (size_t)b * kMaxDet + rank] = (float)cls;
      out[(size_t)kB * kMaxDet * 5 + (size_t)b * kMaxDet + rank] = sv;
    }
  }
}

extern "C" void kernel_launch(void* const* d_in, const int* in_sizes, int n_in,
                              void* d_out, int out_size, void* d_ws, size_t ws_size,
                              hipStream_t stream) {
  (void)in_sizes; (void)n_in; (void)out_size;
  const float* regs = (const float*)d_in[0];
  const float* ctrs = (const float*)d_in[1];
  const float* clfs = (const float*)d_in[2];
  float* out = (float*)d_out;

  const size_t glB  = (size_t)kRows * kCap * sizeof(uint64_t);      // 15.7 MB
  const size_t cbB  = (size_t)kRows * kMaxPC * 4 * sizeof(float);   // 2.0 MB
  const size_t csB  = (size_t)kRows * kMaxPC * sizeof(float);       // 0.5 MB
  const size_t cntB = 8192;                                          // 1280 u32, padded
  if (ws_size < glB + cbB + csB + cntB) return;  // fail visibly, no OOB

  char* p = (char*)d_ws;
  uint64_t* glist   = (uint64_t*)p; p += glB;
  float* cls_boxes  = (float*)p;    p += cbB;
  float* cls_scores = (float*)p;    p += csB;
  uint32_t* gcnt    = (uint32_t*)p;

  zero_cnt_kernel<<<(kRows + 255) / 256, 256, 0, stream>>>(gcnt);
  score_scan_kernel<<<dim3(kGScan, kB), 256, 0, stream>>>(clfs, ctrs, gcnt, glist);
  nms_class_kernel<<<kRows, 256, 0, stream>>>(gcnt, glist, clfs, ctrs, regs,
                                              cls_boxes, cls_scores);
  final_topk_kernel<<<kB, 256, 0, stream>>>(cls_scores, cls_boxes, out);
}

// Round 8
// 289.637 us; speedup vs baseline: 2.5187x; 1.0831x over previous
//
#include <hip/hip_runtime.h>
#include <stdint.h>

// Keep every f32 op un-fused: the reference (numpy/jax f32) computes
// inter = ih*iw; union = a_i + a_j - inter as separate rounded ops. With
// HIP's default -ffp-contract=fast the subtract would fuse into an FMA and
// could flip borderline iou > 0.5 decisions -> wrong box selected.
#pragma clang fp contract(off)

namespace {
constexpr int kN = 21824;      // 128^2 + 64^2 + 32^2 + 16^2 + 8^2
constexpr int kB = 16;
constexpr int kC = 80;
constexpr int kK = 256;        // K_CAND
constexpr int kMaxPC = 100;
constexpr int kMaxDet = 100;
constexpr int kBins1 = 2048;   // level-0 histogram bins (top 11 key bits)
constexpr int kCap = 1536;     // per-row global candidate capacity (u64 keys)
constexpr int kQCap = 320;     // post-refinement qualifier capacity (LDS)
constexpr int kRows = kB * kC; // 1280
constexpr int kTiles = kN / 64;            // 341
constexpr int kTPB = 6;                    // tiles (of 64 anchors) per scan block
constexpr int kGScan = (kTiles + kTPB - 1) / kTPB;   // 57 blocks per batch
constexpr int kLCap = 48;      // per-class per-block LDS list capacity
// Prune floor for the fast path. For this benchmark's product-of-uniforms
// scores, #(s > 0.72) per row ~ mean 950, sd 30 -> inside [kK, kCap] with
// ~10-sigma margin; per-block per-class count ~ mean 17, sd 4 -> < kLCap
// with ~7.8-sigma margin. ANY violation routes to the exact fallback
// (overflow marks the row counter > kCap), so this is a speed heuristic
// only, never a correctness assumption.
constexpr float kThr = 0.72f;
// Exact iou>0.5 without division: RN(inter/unc) > 0.5  <=>  inter > (0.5+2^-25)*unc.
// (0.5+2^-25)*unc is exact in double (25b x 24b mantissa <= 49b); the tie at
// q = 0.5+2^-25 rounds-to-even down to 0.5, so the strict > matches exactly.
constexpr double kIouC = 0x1.000001p-1;   // 0.5 + 2^-25
}

// ---- 48-bit sort key: score bits (high 32) | (0xFFFF - index) (low 16) ----
// scores are >= 0 so the raw f32 bit pattern is order-monotone; the index
// complement reproduces jax top_k's stable tie-break (lower index wins).
__device__ __forceinline__ uint64_t make_key(float s, int n) {
  return ((uint64_t)__float_as_uint(s) << 16) | (uint32_t)(0xFFFF - n);
}

// Block-wide (256 threads) inclusive prefix scan.
__device__ uint32_t block_scan_incl(uint32_t val) {
  __shared__ uint32_t wsum[4];
  int lane = threadIdx.x & 63;
  int wave = threadIdx.x >> 6;
  for (int d = 1; d < 64; d <<= 1) {
    uint32_t t = __shfl_up(val, (unsigned)d, 64);
    if (lane >= d) val += t;
  }
  if (lane == 63) wsum[wave] = val;
  __syncthreads();
  uint32_t off = 0;
  for (int w = 0; w < wave; ++w) off += wsum[w];
  __syncthreads();
  return val + off;
}

// ---- key sources for the refinement select ----
// Fast path: <=6 list keys per thread, held in registers.
struct RegSrc {
  uint64_t k[6];
  int cnt;                      // valid entries in k[] (prefix)
  template <class F> __device__ void each(F f) const {
    #pragma unroll
    for (int j = 0; j < 6; ++j)
      if (j < cnt) f(k[j]);
  }
};
// Exact fallback: recompute scores from the strided class column each pass.
struct ColSrc {
  const float* cl;              // clfs + b*kN*kC + c  (stride kC)
  const float* ct;              // ctrs + b*kN
  template <class F> __device__ void each(F f) const {
    for (int n = threadIdx.x; n < kN; n += 256)
      f(make_key(cl[(size_t)n * kC] * ct[n], n));
  }
};
struct ArrSrc {
  const float* s;
  int count;
  template <class F> __device__ void each(F f) const {
    for (int i = threadIdx.x; i < count; i += 256) f(make_key(s[i], i));
  }
};

// ---- exact top-K floor via histogram refinement, then gather qualifiers.
// Level 0: 11-bit histogram over key bits [37..48). While the qualifier
// count exceeds cap, refine 8 more bits (terminates: the last level pins the
// full 48-bit key -> count == K). Returns Scnt (= #keys >= floor, K <= Scnt
// <= cap) with the qualifiers in cbuf[0..Scnt).
template <class Src>
__device__ int refine_gather(const Src& src, int K, int cap,
                             uint32_t* hist, uint64_t* cbuf) {
  __shared__ int sel_bin;
  __shared__ uint32_t sel_hd, sel_above, qcnt;
  int tid = threadIdx.x;

  for (int i = tid; i < kBins1; i += 256) hist[i] = 0;
  __syncthreads();
  src.each([&](uint64_t k) { atomicAdd(&hist[(uint32_t)(k >> 37)], 1u); });
  __syncthreads();
  uint32_t krem = (uint32_t)K;
  {
    uint32_t bl[8], v = 0;
    int base = kBins1 - 1 - 8 * tid;      // descending scan, 8 bins/thread
    for (int j = 0; j < 8; ++j) { bl[j] = hist[base - j]; v += bl[j]; }
    uint32_t S = block_scan_incl(v);
    if (S >= krem && (S - v) < krem) {
      uint32_t cum = S - v;
      for (int j = 0; j < 8; ++j) {
        cum += bl[j];
        if (cum >= krem) { sel_bin = base - j; sel_hd = bl[j]; sel_above = cum - bl[j]; break; }
      }
    }
    __syncthreads();
  }
  uint64_t prefix = (uint64_t)sel_bin;
  krem = (uint32_t)K - sel_above;
  uint32_t Sge = ((uint32_t)K - krem) + sel_hd;
  int shift = 37;
  __syncthreads();

  while (Sge > (uint32_t)cap) {
    int w = (shift > 8) ? 8 : shift;
    int ns = shift - w, bins = 1 << w, hs = shift;
    for (int i = tid; i < bins; i += 256) hist[i] = 0;
    __syncthreads();
    uint64_t pfx = prefix;
    src.each([&](uint64_t k) {
      if ((k >> hs) == pfx)
        atomicAdd(&hist[(uint32_t)(k >> ns) & (bins - 1)], 1u);
    });
    __syncthreads();
    uint32_t v = (tid < bins) ? hist[bins - 1 - tid] : 0;
    uint32_t S = block_scan_incl(v);
    if (v && S >= krem && (S - v) < krem) {
      sel_bin = bins - 1 - tid; sel_hd = v; sel_above = S - v;
    }
    __syncthreads();
    prefix = (prefix << w) | (uint32_t)sel_bin;
    krem -= sel_above;
    Sge = ((uint32_t)K - krem) + sel_hd;
    shift = ns;
    __syncthreads();
  }

  uint64_t L = prefix << shift;
  if (tid == 0) qcnt = 0;
  __syncthreads();
  src.each([&](uint64_t k) {
    if (k >= L) {
      uint32_t p = atomicAdd(&qcnt, 1u);
      if (p < (uint32_t)cap) cbuf[p] = k;
    }
  });
  __syncthreads();
  int Scnt = (int)qcnt;
  return Scnt > cap ? cap : Scnt;       // == Sge <= cap by construction
}

// ---- zero the per-row candidate counters (d_ws is re-poisoned per call) ----
__global__ __launch_bounds__(256) void zero_cnt_kernel(uint32_t* __restrict__ gcnt) {
  int i = blockIdx.x * 256 + threadIdx.x;
  if (i < kRows) gcnt[i] = 0;
}

// ---- fused score (clf*ctr) + prune, two-level append ----
__global__ __launch_bounds__(256) void score_scan_kernel(
    const float* __restrict__ clfs, const float* __restrict__ ctrs,
    uint32_t* __restrict__ gcnt, uint64_t* __restrict__ glist) {
  int b = blockIdx.y;
  int t0 = blockIdx.x * kTPB;
  int t1 = t0 + kTPB; if (t1 > kTiles) t1 = kTiles;
  int nbase = t0 * 64;
  int nanch = (t1 - t0) * 64;

  __shared__ uint64_t lbuf[kC][kLCap + 1]; // +1 pad: append banks spread
  __shared__ uint32_t lcnt[kC];
  __shared__ uint32_t gbase[kC];
  __shared__ float ct[kTPB * 64];
  int tid = threadIdx.x;
  for (int i = tid; i < kC; i += 256) lcnt[i] = 0;
  for (int i = tid; i < nanch; i += 256) ct[i] = ctrs[(size_t)b * kN + nbase + i];
  __syncthreads();

  const float4* src = (const float4*)(clfs + ((size_t)b * kN + nbase) * kC);
  int n4 = nanch * (kC / 4);             // 20 float4 per anchor
  // software prefetch: issue the next global load before the atomic-laden
  // append body (side effects otherwise pin the loads behind the branches).
  float4 v = (tid < n4) ? src[tid] : float4{0, 0, 0, 0};
  for (int e = tid; e < n4; e += 256) {
    int en = e + 256;
    float4 vn = (en < n4) ? src[en] : float4{0, 0, 0, 0};
    int a = e / 20;                      // anchor within chunk
    int c0 = (e % 20) * 4;               // class of component .x (4 | 80)
    float cv = ct[a];
    int n = nbase + a;
    float sv[4] = {v.x * cv, v.y * cv, v.z * cv, v.w * cv};
    #pragma unroll
    for (int j = 0; j < 4; ++j) {
      if (sv[j] > kThr) {
        int c = c0 + j;
        uint32_t p = atomicAdd(&lcnt[c], 1u);
        if (p < kLCap) lbuf[c][p] = make_key(sv[j], n);
      }
    }
    v = vn;
  }
  __syncthreads();

  // parallel reservations: 80 concurrent global atomics (lanes), then copy.
  if (tid < kC) {
    uint32_t m = lcnt[tid];
    int row = b * kC + tid;
    if (m > kLCap) {                     // overflow -> force exact fallback
      atomicAdd(&gcnt[row], (uint32_t)(kCap + 1));
      gbase[tid] = 0xFFFFFFFFu;
    } else {
      gbase[tid] = m ? atomicAdd(&gcnt[row], m) : 0u;
    }
  }
  __syncthreads();

  int lane = tid & 63, wave = tid >> 6;
  for (int c = wave * 20; c < wave * 20 + 20; ++c) {
    uint32_t m = lcnt[c];
    uint32_t base = gbase[c];
    if (base == 0xFFFFFFFFu || m == 0) continue;
    if (m > kLCap) m = kLCap;
    int row = b * kC + c;
    for (uint32_t i = lane; i < m; i += 64) {
      uint32_t p = base + i;
      if (p < kCap) glist[(size_t)row * kCap + p] = lbuf[c][i];
    }
  }
}

// ---- exact iou>0.5 bit for one candidate pair (reference op order) ----
__device__ __forceinline__ uint64_t iou_bit(const float4& A, float aA,
                                            const float4& Bx, float aB) {
  float yy1 = fmaxf(A.x, Bx.x);
  float yy2 = fminf(A.z, Bx.z);
  float xx1 = fmaxf(A.y, Bx.y);
  float xx2 = fminf(A.w, Bx.w);
  float ih = fmaxf(yy2 - yy1, 0.0f);
  float iw = fmaxf(xx2 - xx1, 0.0f);
  float inter = ih * iw;
  float un = (aB + aA) - inter;
  float unc = fmaxf(un, 1e-8f);
  return (uint64_t)((double)inter > kIouC * (double)unc);
}

// ---- per-(batch,class): list -> exact top-256 -> bit-matrix NMS -> top-100 ----
__global__ __launch_bounds__(256) void nms_class_kernel(
    const uint32_t* __restrict__ gcnt, const uint64_t* __restrict__ glist,
    const float* __restrict__ clfs, const float* __restrict__ ctrs,
    const float* __restrict__ regs,
    float* __restrict__ cls_boxes, float* __restrict__ cls_scores) {
  int row = blockIdx.x;
  int b = row / kC, c = row % kC;
  int tid = threadIdx.x;
  int lane = tid & 63, wave = tid >> 6;

  __shared__ union {
    uint32_t hist[kBins1];               // select phase (8 KB)
    uint64_t supm[kK][4];                // NMS suppression bit-matrix (8 KB)
  } hu;
  __shared__ uint64_t cbuf[kQCap];       // qualifiers (2.5 KB)
  __shared__ uint64_t skey[kK];          // sorted top-256 keys (2 KB)
  __shared__ float4 boxf4[kK];           // y1,x1,y2,x2 (4 KB)
  __shared__ float barea[kK];
  __shared__ uint64_t kinit[4];          // initial keep mask (valid bits)
  __shared__ uint64_t kfin[4];           // final keep mask

  // fast path: pruned list holds a superset of the top-256
  // (cnt >= kK  ==> the 256th-largest score > kThr ==> all top-256 listed;
  //  cnt <= kCap ==> no block overflowed and no append was dropped)
  uint32_t cnt = gcnt[row];
  int Scnt;
  if (cnt >= (uint32_t)kK && cnt <= (uint32_t)kCap) {
    RegSrc rs; rs.cnt = 0;
    const uint64_t* gl = glist + (size_t)row * kCap;
    #pragma unroll
    for (int j = 0; j < 6; ++j) {
      int i = tid + j * 256;
      if (i < (int)cnt) { rs.k[j] = gl[i]; rs.cnt = j + 1; }
    }
    Scnt = refine_gather(rs, kK, kQCap, hu.hist, cbuf);
  } else {
    ColSrc cs{clfs + (size_t)b * kN * kC + c, ctrs + (size_t)b * kN};
    Scnt = refine_gather(cs, kK, kQCap, hu.hist, cbuf);
  }

  // rank-count sort: qualifiers with rank < 256 land sorted in skey
  for (int j = tid; j < Scnt; j += 256) {
    uint64_t kj = cbuf[j];
    int r = 0;
    for (int i = 0; i < Scnt; ++i) r += (cbuf[i] > kj);
    if (r < kK) skey[r] = kj;
  }
  __syncthreads();

  // decode my candidate's box directly from regs (fused decode)
  uint64_t myk = skey[tid];
  int n = 0xFFFF - (int)(myk & 0xFFFF);
  float sc_v = __uint_as_float((uint32_t)(myk >> 16));
  int off, hl;
  float sf;
  if (n < 16384)      { off = 0;     hl = 7; sf = 8.f;   }
  else if (n < 20480) { off = 16384; hl = 6; sf = 16.f;  }
  else if (n < 21504) { off = 20480; hl = 5; sf = 32.f;  }
  else if (n < 21760) { off = 21504; hl = 4; sf = 64.f;  }
  else                { off = 21760; hl = 3; sf = 128.f; }
  int kk = n - off;
  // meshgrid(h, w) with 'xy' indexing -> gy = k % H, gx = k / H
  float gx = (float)(kk >> hl);
  float gy = (float)(kk & ((1 << hl) - 1));
  const float4 r = ((const float4*)regs)[(size_t)b * kN + n];
  float4 mybox;
  mybox.x = (gy - r.z) * sf;             // y1
  mybox.y = (gx - r.x) * sf;             // x1
  mybox.z = (gy + r.w) * sf;             // y2
  mybox.w = (gx + r.y) * sf;             // x2
  float my_a = (mybox.z - mybox.x) * (mybox.w - mybox.y);
  boxf4[tid] = mybox;
  barea[tid] = my_a;
  unsigned long long vm = __ballot(sc_v > 0.05f);   // valid = top_s > CONF_THR
  if (lane == 0) kinit[wave] = vm;
  // zero the suppression matrix (hist no longer needed after select/sort)
  {
    uint64_t* sp = &hu.supm[0][0];
    #pragma unroll
    for (int q = 0; q < 4; ++q) sp[tid + q * 256] = 0;
  }
  __syncthreads();

  // phase A: balanced upper-triangle IoU. Row pair (t, 255-t) has exactly
  // 255 entries; split evenly: threads 0..127 do row t cols [t+1, t+127];
  // thread 128+T does row T cols [T+128, 255] then row 255-T cols
  // [256-T, 255]. Every wave issues ~127-191 iterations (vs 255 before).
  // Bits accumulate in a register word, flushed on 64-bit boundaries via
  // LDS atomicOr (boundary words are shared between two threads).
  if (tid < 128) {
    int t = tid;
    uint64_t cur = 0;
    int jend = t + 127;
    for (int j = t + 1; j <= jend; ++j) {
      cur |= iou_bit(mybox, my_a, boxf4[j], barea[j]) << (j & 63);
      if ((j & 63) == 63) {
        if (cur) atomicOr((unsigned long long*)&hu.supm[t][j >> 6], cur);
        cur = 0;
      }
    }
    if (cur) atomicOr((unsigned long long*)&hu.supm[t][jend >> 6], cur);
  } else {
    int T = tid - 128;
    float4 bA = boxf4[T]; float aA = barea[T];
    uint64_t cur = 0;
    for (int j = T + 128; j <= 255; ++j) {
      cur |= iou_bit(bA, aA, boxf4[j], barea[j]) << (j & 63);
      if ((j & 63) == 63) {
        if (cur) atomicOr((unsigned long long*)&hu.supm[T][j >> 6], cur);
        cur = 0;
      }
    }
    if (T > 0) {
      int rB = 255 - T;
      float4 bB = boxf4[rB]; float aB = barea[rB];
      for (int j = 256 - T; j <= 255; ++j) {
        cur |= iou_bit(bB, aB, boxf4[j], barea[j]) << (j & 63);
        if ((j & 63) == 63) {
          if (cur) atomicOr((unsigned long long*)&hu.supm[rB][j >> 6], cur);
          cur = 0;
        }
      }
    }
  }
  __syncthreads();

  // phase B: greedy resolution by wave 0 only. Rows are prefetched in
  // chunks of 4 (address-independent LDS loads overlap the serial VALU
  // apply chain); no LDS latency inside the dependency chain.
  if (wave == 0) {
    uint64_t kw0 = kinit[0], kw1 = kinit[1], kw2 = kinit[2], kw3 = kinit[3];
    #define NMS_SECTION(W, KW)                                              \
      _Pragma("unroll")                                                     \
      for (int ch = 0; ch < 16; ++ch) {                                     \
        const uint64_t* s0 = hu.supm[(W << 6) + ch * 4 + 0];                \
        const uint64_t* s1 = hu.supm[(W << 6) + ch * 4 + 1];                \
        const uint64_t* s2 = hu.supm[(W << 6) + ch * 4 + 2];                \
        const uint64_t* s3 = hu.supm[(W << 6) + ch * 4 + 3];                \
        uint64_t a0 = s0[0], a1 = s0[1], a2 = s0[2], a3 = s0[3];            \
        uint64_t b0 = s1[0], b1 = s1[1], b2 = s1[2], b3 = s1[3];            \
        uint64_t c0 = s2[0], c1 = s2[1], c2 = s2[2], c3 = s2[3];            \
        uint64_t d0 = s3[0], d1 = s3[1], d2 = s3[2], d3 = s3[3];            \
        if ((KW >> (ch * 4 + 0)) & 1ull) { kw0 &= ~a0; kw1 &= ~a1; kw2 &= ~a2; kw3 &= ~a3; } \
        if ((KW >> (ch * 4 + 1)) & 1ull) { kw0 &= ~b0; kw1 &= ~b1; kw2 &= ~b2; kw3 &= ~b3; } \
        if ((KW >> (ch * 4 + 2)) & 1ull) { kw0 &= ~c0; kw1 &= ~c1; kw2 &= ~c2; kw3 &= ~c3; } \
        if ((KW >> (ch * 4 + 3)) & 1ull) { kw0 &= ~d0; kw1 &= ~d1; kw2 &= ~d2; kw3 &= ~d3; } \
      }
    NMS_SECTION(0, kw0)
    NMS_SECTION(1, kw1)
    NMS_SECTION(2, kw2)
    NMS_SECTION(3, kw3)
    #undef NMS_SECTION
    if (lane == 0) { kfin[0] = kw0; kfin[1] = kw1; kfin[2] = kw2; kfin[3] = kw3; }
  }
  __syncthreads();

  uint64_t kw0 = kfin[0], kw1 = kfin[1], kw2 = kfin[2], kw3 = kfin[3];
  uint64_t ww = (wave == 0) ? kw0 : (wave == 1) ? kw1 : (wave == 2) ? kw2 : kw3;
  bool keptf = (ww >> lane) & 1ull;
  int kept_total = (int)(__popcll(kw0) + __popcll(kw1) +
                         __popcll(kw2) + __popcll(kw3));
  int kept_before = (int)__popcll(ww & ((1ull << lane) - 1ull));
  if (wave > 0) kept_before += (int)__popcll(kw0);
  if (wave > 1) kept_before += (int)__popcll(kw1);
  if (wave > 2) kept_before += (int)__popcll(kw2);

  // stable top-100 of kept scores: kept candidates are already in descending
  // (score,-index) order; zero slots tie-break by position. Final order =
  // kept (tid order) then suppressed (tid order) == reference stable top_k.
  int rank2 = keptf ? kept_before : (kept_total + tid - kept_before);
  if (rank2 < kMaxPC) {
    float ks = keptf ? sc_v : 0.0f;
    size_t obase = ((size_t)row) * kMaxPC + rank2;
    cls_scores[obase] = ks;
    float* ob = cls_boxes + obase * 4;
    ob[0] = mybox.x; ob[1] = mybox.y; ob[2] = mybox.z; ob[3] = mybox.w;
  }
}

// ---- per-batch: stable top-100 over 80*100 entries, write final outputs ----
__global__ __launch_bounds__(256) void final_topk_kernel(
    const float* __restrict__ cls_scores, const float* __restrict__ cls_boxes,
    float* __restrict__ out) {
  int b = blockIdx.x;
  int tid = threadIdx.x;
  const int M = kC * kMaxPC;  // 8000
  __shared__ uint32_t hist[kBins1];
  __shared__ uint64_t cbuf[kQCap];

  ArrSrc as{cls_scores + (size_t)b * M, M};
  int Scnt = refine_gather(as, kMaxDet, kQCap, hist, cbuf);

  // rank-count: ranks < 100 are the final detections, sorted
  for (int j = tid; j < Scnt; j += 256) {
    uint64_t myk = cbuf[j];
    int rank = 0;
    for (int i = 0; i < Scnt; ++i) rank += (cbuf[i] > myk);
    if (rank < kMaxDet) {
      float sv = __uint_as_float((uint32_t)(myk >> 16));
      int f = 0xFFFF - (int)(myk & 0xFFFF);
      int cls = f / 100;
      const float* bp = cls_boxes + ((size_t)b * M + f) * 4;
      float m = (sv > 0.0f) ? 1.0f : 0.0f; // fin_b zeroed where fin_s <= 0
      float* ob = out + ((size_t)b * kMaxDet + rank) * 4;
      ob[0] = bp[0] * m; ob[1] = bp[1] * m; ob[2] = bp[2] * m; ob[3] = bp[3] * m;
      out[(size_t)kB * kMaxDet * 4 + (size_t)b * kMaxDet + rank] = (float)cls;
      out[(size_t)kB * kMaxDet * 5 + (size_t)b * kMaxDet + rank] = sv;
    }
  }
}

extern "C" void kernel_launch(void* const* d_in, const int* in_sizes, int n_in,
                              void* d_out, int out_size, void* d_ws, size_t ws_size,
                              hipStream_t stream) {
  (void)in_sizes; (void)n_in; (void)out_size;
  const float* regs = (const float*)d_in[0];
  const float* ctrs = (const float*)d_in[1];
  const float* clfs = (const float*)d_in[2];
  float* out = (float*)d_out;

  const size_t glB  = (size_t)kRows * kCap * sizeof(uint64_t);      // 15.7 MB
  const size_t cbB  = (size_t)kRows * kMaxPC * 4 * sizeof(float);   // 2.0 MB
  const size_t csB  = (size_t)kRows * kMaxPC * sizeof(float);       // 0.5 MB
  const size_t cntB = 8192;                                          // 1280 u32, padded
  if (ws_size < glB + cbB + csB + cntB) return;  // fail visibly, no OOB

  char* p = (char*)d_ws;
  uint64_t* glist   = (uint64_t*)p; p += glB;
  float* cls_boxes  = (float*)p;    p += cbB;
  float* cls_scores = (float*)p;    p += csB;
  uint32_t* gcnt    = (uint32_t*)p;

  zero_cnt_kernel<<<(kRows + 255) / 256, 256, 0, stream>>>(gcnt);
  score_scan_kernel<<<dim3(kGScan, kB), 256, 0, stream>>>(clfs, ctrs, gcnt, glist);
  nms_class_kernel<<<kRows, 256, 0, stream>>>(gcnt, glist, clfs, ctrs, regs,
                                              cls_boxes, cls_scores);
  final_topk_kernel<<<kB, 256, 0, stream>>>(cls_scores, cls_boxes, out);
}